// Round 18
// baseline (105.470 us; speedup 1.0000x reference)
//
#include <hip/hip_runtime.h>
#include <hip/hip_bf16.h>
#include <math.h>
#include <stdint.h>

typedef __attribute__((ext_vector_type(8))) short bf16x8;
typedef __attribute__((ext_vector_type(4))) float f32x4;

__device__ __forceinline__ uint32_t pack2(float a, float b) {
    union { __hip_bfloat162 h2; uint32_t u; } c;
    c.h2 = __float22bfloat162_rn(make_float2(a, b));   // v_cvt_pk_bf16_f32
    return c.u;
}
__device__ __forceinline__ unsigned short f2bf(float f) {
    union { __hip_bfloat16 h; unsigned short u; } c;
    c.h = __float2bfloat16(f);
    return c.u;
}
__device__ __forceinline__ float bf2f(unsigned short h) {
    union { uint32_t u; float f; } c; c.u = ((uint32_t)h) << 16;
    return c.f;
}
__device__ __forceinline__ float silu_f(float x) {
    return x / (1.0f + __expf(-x));
}

// Uniform cardinal cubic B-spline bases on grid g_i = -2.2 + 0.4*i.
// Identical to the reference Cox-de-Boor recursion on this uniform grid.
__device__ __forceinline__ void bspline8(float x, float* __restrict__ b) {
    const float tt = (x + 2.2f) * 2.5f;
#pragma unroll
    for (int v = 0; v < 8; ++v) {
        float y = fabsf(tt - (float)(v + 2));
        float p = fmaxf(2.0f - y, 0.0f);
        float q = fmaxf(1.0f - y, 0.0f);
        b[v] = (p * p * p - 4.0f * q * q * q) * (1.0f / 6.0f);
    }
}

__device__ __forceinline__ void gload16(const void* g, void* l) {
    __builtin_amdgcn_global_load_lds(
        (const __attribute__((address_space(1))) void*)g,
        (__attribute__((address_space(3))) void*)l, 16, 0, 0);
}

// ---------------------------------------------------------------------------
// prep kernels
// ---------------------------------------------------------------------------
__global__ __launch_bounds__(256) void prep_ftw(const float* __restrict__ ftw,
                                                unsigned short* __restrict__ Wb) {
    const int idx = blockIdx.x * 256 + threadIdx.x;   // 98304 = 128*768
    Wb[idx] = f2bf(ftw[idx]);
}

// Bp -> fragment-contiguous bf16: [jb(32)][wc(4)][nt(2)][ks(4)][l(64)][e(8)]
//   col = wc*32 + nt*16 + (l&15);  k = jb*128 + ks*32 + (l>>4)*8 + e
__global__ __launch_bounds__(256) void prep_bpf(const float* __restrict__ bw,
                                                const float* __restrict__ sw,
                                                unsigned short* __restrict__ BpF) {
    const int idx = blockIdx.x * 256 + threadIdx.x;   // 524288 = 32*16384
    const int e = idx & 7, l = (idx >> 3) & 63, ks = (idx >> 9) & 3;
    const int nt = (idx >> 11) & 1, wc = (idx >> 12) & 3, jb = idx >> 14;
    const int col = wc * 32 + nt * 16 + (l & 15);
    const int k = jb * 128 + ks * 32 + (l >> 4) * 8 + e;
    const int f = k >> 4, v = k & 15;
    float val = 0.f;
    if (v == 0) val = bw[col * 256 + f];
    else if (v <= 8) val = sw[(size_t)(col * 256 + f) * 8 + (v - 1)];
    BpF[idx] = f2bf(val);
}

// ---------------------------------------------------------------------------
// FUSED, BM=64, 2 blocks/CU (LDS 80 KB).  Per 64-row tile:
//   Phase 1: FT GEMM both sides (12 BK=128 tiles), depth-2 reg prefetch of A
//            (named reg sets, counted vmcnt(4)), Wb via gload_lds with
//            pre-swizzled source.  H -> smHT, LDS only.  [identical to r17]
//   Phase 2: KAN1 expanded-A GEMM in 16 SUPERSTEPS of 256 k (2 jb-blocks per
//            barrier pair -- phi is one 32 KB [64][256k] buffer in the
//            smA+smB region freed by reg-resident B).  Each thread expands
//            2 features/superstep; both Bp fragment sets (bfA/bfB) issued at
//            step-top so the 2nd set's L2 latency hides under the first 16
//            MFMA.  Barrier events halve vs r17 (64 -> 32).
//   Phase 3: KAN2 reduce + sigmoid.
// grid 512, block 512 (8 waves as 2x4; wave tile 32r x 32c both GEMMs).
// ---------------------------------------------------------------------------
__global__ __launch_bounds__(512, 4) void kan_fused(
        const float* __restrict__ stm, const float* __restrict__ nstm,
        const unsigned short* __restrict__ Wb, const float* __restrict__ bias,
        const unsigned short* __restrict__ BpF,
        const float* __restrict__ w2b, const float* __restrict__ w2s,
        float* __restrict__ out) {
    __shared__ alignas(16) char lds[81920];
    char* smA  = lds;            // ph1: A tile 64x128 bf16 swizzled (16 KB)
    char* smB  = lds + 16384;    // ph1: Wb tile 128x128 bf16 swizzled (32 KB)
    char* phi  = lds;            // ph2: phi [64 rows][256 k] bf16 (32 KB)
    char* smHT = lds + 49152;    // H^T [256 feat][64 rows] bf16, swizzled

    const int r0 = blockIdx.x * 64;
    const int t = threadIdx.x;
    const int l = t & 63, w = t >> 6;
    const int fr = l & 15, h = l >> 4;
    const int wr = w >> 2, wc = w & 3;        // 2x4 wave grid, tile 32r x 32c

    // A staging geometry: thread -> row (t>>3), 16 floats at col (t&7)*16
    const int arow = t >> 3;
    const int acol = (t & 7) * 16;
    const uint32_t adst0 = (uint32_t)arow * 256u +
        ((uint32_t)(((t & 7) * 2) ^ (arow & 15)) << 4);
    const uint32_t adst1 = (uint32_t)arow * 256u +
        ((uint32_t)(((t & 7) * 2 + 1) ^ (arow & 15)) << 4);
    const int gidx = w * 4;                   // gload instr base index

    f32x4 acc[2][2];
#pragma unroll
    for (int mt = 0; mt < 2; ++mt)
#pragma unroll
        for (int nt = 0; nt < 2; ++nt) acc[mt][nt] = (f32x4){0.f, 0.f, 0.f, 0.f};

    float4 regY[4], regZ[4];
    bf16x8 bfA[2][4], bfB[2][4];   // phase-2 B fragments (static indexing)

#define FT_ISSUE(REG, TK)                                                      \
    {                                                                          \
        const float* __restrict__ Ap = ((TK) >= 6) ? nstm : stm;               \
        const int kk = ((TK) % 6) * 128;                                       \
        _Pragma("unroll") for (int q = 0; q < 4; ++q)                          \
            REG[q] = *reinterpret_cast<const float4*>(                         \
                &Ap[(size_t)(r0 + arow) * 768 + kk + acol + q * 4]);           \
    }

#define FT_WRITE(REG)                                                          \
    {                                                                          \
        int4 w0, w1;                                                           \
        w0.x = (int)pack2(REG[0].x, REG[0].y);                                 \
        w0.y = (int)pack2(REG[0].z, REG[0].w);                                 \
        w0.z = (int)pack2(REG[1].x, REG[1].y);                                 \
        w0.w = (int)pack2(REG[1].z, REG[1].w);                                 \
        w1.x = (int)pack2(REG[2].x, REG[2].y);                                 \
        w1.y = (int)pack2(REG[2].z, REG[2].w);                                 \
        w1.z = (int)pack2(REG[3].x, REG[3].y);                                 \
        w1.w = (int)pack2(REG[3].z, REG[3].w);                                 \
        *reinterpret_cast<int4*>(smA + adst0) = w0;                            \
        *reinterpret_cast<int4*>(smA + adst1) = w1;                            \
    }

#define GLOADB_FT(K0)                                                          \
    _Pragma("unroll") for (int j = 0; j < 4; ++j) {                            \
        const int col = (gidx + j) * 4 + (l >> 4);                             \
        gload16(&Wb[(size_t)col * 768 + (K0) + (((l & 15) ^ (col & 15)) << 3)],\
                smB + (gidx + j) * 1024);                                      \
    }

// phase-2: B fragments, one fully-coalesced 1 KB load per (nt,ks)
#define LOADF(BF, JB)                                                          \
    {                                                                          \
        const unsigned short* __restrict__ fb =                                \
            BpF + (size_t)(JB) * 16384 + wc * 4096 + l * 8;                    \
        _Pragma("unroll") for (int nt = 0; nt < 2; ++nt)                       \
            _Pragma("unroll") for (int ks = 0; ks < 4; ++ks)                   \
                BF[nt][ks] = *reinterpret_cast<const bf16x8*>(                 \
                    fb + nt * 2048 + ks * 512);                                \
    }

#define GEMM_STEP_LDS()                                                        \
    _Pragma("unroll") for (int ks = 0; ks < 4; ++ks) {                         \
        bf16x8 a[2], b[2];                                                     \
        _Pragma("unroll") for (int mt = 0; mt < 2; ++mt) {                     \
            const uint32_t row = (uint32_t)(wr * 32 + mt * 16 + fr);           \
            a[mt] = *reinterpret_cast<const bf16x8*>(                          \
                smA + row * 256u +                                             \
                (((uint32_t)(ks * 4 + h) ^ (row & 15u)) << 4));                \
        }                                                                      \
        _Pragma("unroll") for (int nt = 0; nt < 2; ++nt) {                     \
            const uint32_t col = (uint32_t)(wc * 32 + nt * 16 + fr);           \
            b[nt] = *reinterpret_cast<const bf16x8*>(                          \
                smB + col * 256u +                                             \
                (((uint32_t)(ks * 4 + h) ^ (col & 15u)) << 4));                \
        }                                                                      \
        _Pragma("unroll") for (int mt = 0; mt < 2; ++mt)                       \
            _Pragma("unroll") for (int nt = 0; nt < 2; ++nt)                   \
                acc[mt][nt] = __builtin_amdgcn_mfma_f32_16x16x32_bf16(         \
                    a[mt], b[nt], acc[mt][nt], 0, 0, 0);                       \
    }

// phase-2 MFMA over 256 k: first 4 ks-chunks use bfA, next 4 use bfB.
// phi rows are 512 B = 32 chunks; chunk index XOR-swizzled with row&15.
#define GEMM_REG8()                                                            \
    _Pragma("unroll") for (int ks = 0; ks < 4; ++ks) {                         \
        bf16x8 a[2];                                                           \
        _Pragma("unroll") for (int mt = 0; mt < 2; ++mt) {                     \
            const uint32_t row = (uint32_t)(wr * 32 + mt * 16 + fr);           \
            a[mt] = *reinterpret_cast<const bf16x8*>(                          \
                phi + row * 512u +                                             \
                (((uint32_t)(ks * 4 + h) ^ (row & 15u)) << 4));                \
        }                                                                      \
        _Pragma("unroll") for (int mt = 0; mt < 2; ++mt)                       \
            _Pragma("unroll") for (int nt = 0; nt < 2; ++nt)                   \
                acc[mt][nt] = __builtin_amdgcn_mfma_f32_16x16x32_bf16(         \
                    a[mt], bfA[nt][ks], acc[mt][nt], 0, 0, 0);                 \
    }                                                                          \
    _Pragma("unroll") for (int ks = 0; ks < 4; ++ks) {                         \
        bf16x8 a[2];                                                           \
        _Pragma("unroll") for (int mt = 0; mt < 2; ++mt) {                     \
            const uint32_t row = (uint32_t)(wr * 32 + mt * 16 + fr);           \
            a[mt] = *reinterpret_cast<const bf16x8*>(                          \
                phi + row * 512u +                                             \
                (((uint32_t)(16 + ks * 4 + h) ^ (row & 15u)) << 4));           \
        }                                                                      \
        _Pragma("unroll") for (int mt = 0; mt < 2; ++mt)                       \
            _Pragma("unroll") for (int nt = 0; nt < 2; ++nt)                   \
                acc[mt][nt] = __builtin_amdgcn_mfma_f32_16x16x32_bf16(         \
                    a[mt], bfB[nt][ks], acc[mt][nt], 0, 0, 0);                 \
    }

#define DUMP_H(SO)                                                             \
    _Pragma("unroll") for (int nt = 0; nt < 2; ++nt) {                         \
        const int col = wc * 32 + nt * 16 + fr;                                \
        const float bv = bias[col];                                            \
        const int feat = (SO) + col;                                           \
        _Pragma("unroll") for (int mt = 0; mt < 2; ++mt) {                     \
            const int rowb = wr * 32 + mt * 16 + h * 4;                        \
            int2 o;                                                            \
            o.x = (int)pack2(acc[mt][nt][0] + bv, acc[mt][nt][1] + bv);        \
            o.y = (int)pack2(acc[mt][nt][2] + bv, acc[mt][nt][3] + bv);        \
            const uint32_t db = (uint32_t)feat * 128u +                        \
                ((uint32_t)((rowb >> 3) ^ (feat & 7)) << 4) +                  \
                (uint32_t)(rowb & 7) * 2u;                                     \
            *reinterpret_cast<int2*>(smHT + db) = o;                           \
            acc[mt][nt] = (f32x4){0.f, 0.f, 0.f, 0.f};                         \
        }                                                                      \
    }

#define LGKM_BAR()                                                             \
    asm volatile("s_waitcnt lgkmcnt(0)" ::: "memory");                         \
    __builtin_amdgcn_sched_barrier(0);                                         \
    __builtin_amdgcn_s_barrier();

    // ================= Phase 1: feature transform (both sides) =============
    FT_ISSUE(regY, 0);
    FT_ISSUE(regZ, 1);
#pragma unroll 1
    for (int pp = 0; pp < 6; ++pp) {
        // ---- even slot: tile 2pp ----
        FT_WRITE(regY);                       // compiler waits regY's loads
        GLOADB_FT(((2 * pp) % 6) * 128);
        __builtin_amdgcn_sched_barrier(0);    // pin: B gloads older than A issue
        if (pp < 5) {
            FT_ISSUE(regY, 2 * pp + 2);
            asm volatile("s_waitcnt vmcnt(4)" ::: "memory");   // B done, A flying
        } else {
            asm volatile("s_waitcnt vmcnt(0)" ::: "memory");
        }
        asm volatile("s_waitcnt lgkmcnt(0)" ::: "memory");
        __builtin_amdgcn_sched_barrier(0);
        __builtin_amdgcn_s_barrier();
        __builtin_amdgcn_s_setprio(1);
        GEMM_STEP_LDS();
        __builtin_amdgcn_s_setprio(0);
        LGKM_BAR();
        // ---- odd slot: tile 2pp+1 ----
        FT_WRITE(regZ);
        GLOADB_FT(((2 * pp + 1) % 6) * 128);
        __builtin_amdgcn_sched_barrier(0);
        if (pp < 5) {
            FT_ISSUE(regZ, 2 * pp + 3);
            asm volatile("s_waitcnt vmcnt(4)" ::: "memory");
        } else {
            asm volatile("s_waitcnt vmcnt(0)" ::: "memory");
        }
        asm volatile("s_waitcnt lgkmcnt(0)" ::: "memory");
        __builtin_amdgcn_sched_barrier(0);
        __builtin_amdgcn_s_barrier();
        __builtin_amdgcn_s_setprio(1);
        GEMM_STEP_LDS();
        __builtin_amdgcn_s_setprio(0);
        if (pp == 2) { DUMP_H(0); }           // side 0 complete
        if (pp == 5) { DUMP_H(128); }         // side 1 complete
        LGKM_BAR();
    }

    // ================= Phase 2: KAN1 GEMM, 16 supersteps of 256 k ==========
#pragma unroll 1
    for (int sb = 0; sb < 16; ++sb) {
        // 1. both Bp fragment sets -> regs (2nd set's latency hides under
        //    expansion VALU + first MFMA half)
        LOADF(bfA, 2 * sb);
        LOADF(bfB, 2 * sb + 1);
        __builtin_amdgcn_sched_barrier(0);
        // 2. expansion: 2 features per thread (lf = w and w+8), row l
#pragma unroll
        for (int e = 0; e < 2; ++e) {
            const int lf = w + e * 8;              // local feature 0..15
            const int feat = sb * 16 + lf;
            const unsigned short xv = *reinterpret_cast<const unsigned short*>(
                smHT + (uint32_t)feat * 128u +
                ((uint32_t)((l >> 3) ^ (feat & 7)) << 4) + (uint32_t)(l & 7) * 2u);
            const float x = bf2f(xv);
            float bs[8];
            bspline8(x, bs);
            const uint32_t pw0 = pack2(silu_f(x), bs[0]);
            const uint32_t pw1 = pack2(bs[1], bs[2]);
            const uint32_t pw2 = pack2(bs[3], bs[4]);
            const uint32_t pw3 = pack2(bs[5], bs[6]);
            const uint32_t pw4 = pack2(bs[7], 0.f);
            const uint32_t d0 = (uint32_t)l * 512u +
                ((uint32_t)((2 * lf) ^ (l & 15)) << 4);
            const uint32_t d1 = (uint32_t)l * 512u +
                ((uint32_t)((2 * lf + 1) ^ (l & 15)) << 4);
            *reinterpret_cast<int4*>(phi + d0) =
                make_int4((int)pw0, (int)pw1, (int)pw2, (int)pw3);
            *reinterpret_cast<int4*>(phi + d1) = make_int4((int)pw4, 0, 0, 0);
        }
        asm volatile("s_waitcnt lgkmcnt(0)" ::: "memory");
        __builtin_amdgcn_sched_barrier(0);
        __builtin_amdgcn_s_barrier();
        __builtin_amdgcn_s_setprio(1);
        GEMM_REG8();
        __builtin_amdgcn_s_setprio(0);
        LGKM_BAR();
    }

    // ================= Phase 3: KAN2 + sigmoid =============================
    unsigned short* smH2 = (unsigned short*)lds;   // reuse phi region
#pragma unroll
    for (int mt = 0; mt < 2; ++mt)
#pragma unroll
        for (int nt = 0; nt < 2; ++nt) {
            const int col = wc * 32 + nt * 16 + fr;
#pragma unroll
            for (int j = 0; j < 4; ++j) {
                const int row = wr * 32 + mt * 16 + h * 4 + j;
                smH2[row * 136 + col] = f2bf(acc[mt][nt][j]);
            }
        }
    __syncthreads();
    const int row2 = t >> 3, qd = t & 7;           // 8 threads/row, 16 cols each
    float sum = 0.f;
#pragma unroll 4
    for (int i = 0; i < 16; ++i) {
        const int j = qd * 16 + ((i + qd * 2) & 15);   // stagger banks
        const float x = bf2f(smH2[row2 * 136 + j]);
        float bs[8];
        bspline8(x, bs);
        const float4 s0 = *reinterpret_cast<const float4*>(&w2s[j * 8]);
        const float4 s1 = *reinterpret_cast<const float4*>(&w2s[j * 8 + 4]);
        float s = silu_f(x) * w2b[j];
        s += bs[0] * s0.x + bs[1] * s0.y + bs[2] * s0.z + bs[3] * s0.w;
        s += bs[4] * s1.x + bs[5] * s1.y + bs[6] * s1.z + bs[7] * s1.w;
        sum += s;
    }
    sum += __shfl_xor(sum, 1, 64);
    sum += __shfl_xor(sum, 2, 64);
    sum += __shfl_xor(sum, 4, 64);
    if (qd == 0) out[r0 + row2] = 1.0f / (1.0f + __expf(-sum));
}

// ---------------------------------------------------------------------------
extern "C" void kernel_launch(void* const* d_in, const int* in_sizes, int n_in,
                              void* d_out, int out_size, void* d_ws, size_t ws_size,
                              hipStream_t stream) {
    const float* stm  = (const float*)d_in[0];
    const float* nstm = (const float*)d_in[1];
    const float* ft_w = (const float*)d_in[2];
    const float* ft_b = (const float*)d_in[3];
    const float* k1bw = (const float*)d_in[4];
    const float* k1sw = (const float*)d_in[5];
    const float* k2bw = (const float*)d_in[6];
    const float* k2sw = (const float*)d_in[7];
    float* out = (float*)d_out;

    char* ws = (char*)d_ws;
    unsigned short* Wb  = (unsigned short*)ws;                //   196,608 B
    unsigned short* BpF = (unsigned short*)(ws + 196608);     // 1,048,576 B

    prep_ftw<<<384, 256, 0, stream>>>(ft_w, Wb);
    prep_bpf<<<2048, 256, 0, stream>>>(k1bw, k1sw, BpF);
    kan_fused<<<512, 512, 0, stream>>>(stm, nstm, Wb, ft_b, BpF, k2bw, k2sw, out);
}

// Round 19
// 104.422 us; speedup vs baseline: 1.0100x; 1.0100x over previous
//
#include <hip/hip_runtime.h>
#include <hip/hip_bf16.h>
#include <math.h>
#include <stdint.h>

typedef __attribute__((ext_vector_type(8))) short bf16x8;
typedef __attribute__((ext_vector_type(4))) float f32x4;

__device__ __forceinline__ uint32_t pack2(float a, float b) {
    union { __hip_bfloat162 h2; uint32_t u; } c;
    c.h2 = __float22bfloat162_rn(make_float2(a, b));   // v_cvt_pk_bf16_f32
    return c.u;
}
__device__ __forceinline__ unsigned short f2bf(float f) {
    union { __hip_bfloat16 h; unsigned short u; } c;
    c.h = __float2bfloat16(f);
    return c.u;
}
__device__ __forceinline__ float bf2f(unsigned short h) {
    union { uint32_t u; float f; } c; c.u = ((uint32_t)h) << 16;
    return c.f;
}
__device__ __forceinline__ float silu_f(float x) {
    return x / (1.0f + __expf(-x));
}

// Uniform cardinal cubic B-spline bases on grid g_i = -2.2 + 0.4*i.
// Identical to the reference Cox-de-Boor recursion on this uniform grid.
__device__ __forceinline__ void bspline8(float x, float* __restrict__ b) {
    const float tt = (x + 2.2f) * 2.5f;
#pragma unroll
    for (int v = 0; v < 8; ++v) {
        float y = fabsf(tt - (float)(v + 2));
        float p = fmaxf(2.0f - y, 0.0f);
        float q = fmaxf(1.0f - y, 0.0f);
        b[v] = (p * p * p - 4.0f * q * q * q) * (1.0f / 6.0f);
    }
}

__device__ __forceinline__ void gload16(const void* g, void* l) {
    __builtin_amdgcn_global_load_lds(
        (const __attribute__((address_space(1))) void*)g,
        (__attribute__((address_space(3))) void*)l, 16, 0, 0);
}

// ---------------------------------------------------------------------------
// prep kernels
// ---------------------------------------------------------------------------
__global__ __launch_bounds__(256) void prep_ftw(const float* __restrict__ ftw,
                                                unsigned short* __restrict__ Wb) {
    const int idx = blockIdx.x * 256 + threadIdx.x;   // 98304 = 128*768
    Wb[idx] = f2bf(ftw[idx]);
}

// Bp -> fragment-contiguous bf16: [jb(32)][wc(4)][nt(2)][ks(4)][l(64)][e(8)]
//   col = wc*32 + nt*16 + (l&15);  k = jb*128 + ks*32 + (l>>4)*8 + e
__global__ __launch_bounds__(256) void prep_bpf(const float* __restrict__ bw,
                                                const float* __restrict__ sw,
                                                unsigned short* __restrict__ BpF) {
    const int idx = blockIdx.x * 256 + threadIdx.x;   // 524288 = 32*16384
    const int e = idx & 7, l = (idx >> 3) & 63, ks = (idx >> 9) & 3;
    const int nt = (idx >> 11) & 1, wc = (idx >> 12) & 3, jb = idx >> 14;
    const int col = wc * 32 + nt * 16 + (l & 15);
    const int k = jb * 128 + ks * 32 + (l >> 4) * 8 + e;
    const int f = k >> 4, v = k & 15;
    float val = 0.f;
    if (v == 0) val = bw[col * 256 + f];
    else if (v <= 8) val = sw[(size_t)(col * 256 + f) * 8 + (v - 1)];
    BpF[idx] = f2bf(val);
}

// ---------------------------------------------------------------------------
// FUSED, BM=64, 2 blocks/CU (LDS 80 KB).  Per 64-row tile:
//   Phase 1: FT GEMM both sides (12 BK=128 tiles), depth-2 reg prefetch of A
//            (named reg sets, counted vmcnt(4)), Wb via gload_lds with
//            pre-swizzled source.  H -> smHT (transposed [256][64] bf16,
//            chunk-XOR swizzled) -- LDS only.
//   Phase 2: KAN1 expanded-A GEMM, 32 jb-steps; Bp FRAGMENT-CONTIGUOUS
//            direct global->reg (issued before expansion; L2 latency hides
//            under the ~110-op spline VALU).  No b-side LDS reads, no smB
//            staging, no vmcnt drains in this phase.
//   Phase 3: KAN2 reduce + sigmoid.
// grid 512, block 512 (8 waves as 2x4; wave tile 32r x 32c both GEMMs).
// Session best: 104.2 us total (642 us fp32 baseline -> 6.2x).
// ---------------------------------------------------------------------------
__global__ __launch_bounds__(512, 4) void kan_fused(
        const float* __restrict__ stm, const float* __restrict__ nstm,
        const unsigned short* __restrict__ Wb, const float* __restrict__ bias,
        const unsigned short* __restrict__ BpF,
        const float* __restrict__ w2b, const float* __restrict__ w2s,
        float* __restrict__ out) {
    __shared__ alignas(16) char lds[81920];
    char* smA  = lds;            // 16 KB: A/phi tile 64 x 128 bf16, swizzled
    char* smB  = lds + 16384;    // 32 KB: ph1 Wb tile 128 x 128 bf16, swizzled
    char* smHT = lds + 49152;    // 32 KB: H^T [256 feat][64 rows] bf16, swizzled

    const int r0 = blockIdx.x * 64;
    const int t = threadIdx.x;
    const int l = t & 63, w = t >> 6;
    const int fr = l & 15, h = l >> 4;
    const int wr = w >> 2, wc = w & 3;        // 2x4 wave grid, tile 32r x 32c

    // A staging geometry: thread -> row (t>>3), 16 floats at col (t&7)*16
    const int arow = t >> 3;
    const int acol = (t & 7) * 16;
    const uint32_t adst0 = (uint32_t)arow * 256u +
        ((uint32_t)(((t & 7) * 2) ^ (arow & 15)) << 4);
    const uint32_t adst1 = (uint32_t)arow * 256u +
        ((uint32_t)(((t & 7) * 2 + 1) ^ (arow & 15)) << 4);
    const int gidx = w * 4;                   // gload instr base index

    f32x4 acc[2][2];
#pragma unroll
    for (int mt = 0; mt < 2; ++mt)
#pragma unroll
        for (int nt = 0; nt < 2; ++nt) acc[mt][nt] = (f32x4){0.f, 0.f, 0.f, 0.f};

    float4 regY[4], regZ[4];
    bf16x8 bf[2][4];   // phase-2 B fragments (static indexing only)

#define FT_ISSUE(REG, TK)                                                      \
    {                                                                          \
        const float* __restrict__ Ap = ((TK) >= 6) ? nstm : stm;               \
        const int kk = ((TK) % 6) * 128;                                       \
        _Pragma("unroll") for (int q = 0; q < 4; ++q)                          \
            REG[q] = *reinterpret_cast<const float4*>(                         \
                &Ap[(size_t)(r0 + arow) * 768 + kk + acol + q * 4]);           \
    }

#define FT_WRITE(REG)                                                          \
    {                                                                          \
        int4 w0, w1;                                                           \
        w0.x = (int)pack2(REG[0].x, REG[0].y);                                 \
        w0.y = (int)pack2(REG[0].z, REG[0].w);                                 \
        w0.z = (int)pack2(REG[1].x, REG[1].y);                                 \
        w0.w = (int)pack2(REG[1].z, REG[1].w);                                 \
        w1.x = (int)pack2(REG[2].x, REG[2].y);                                 \
        w1.y = (int)pack2(REG[2].z, REG[2].w);                                 \
        w1.z = (int)pack2(REG[3].x, REG[3].y);                                 \
        w1.w = (int)pack2(REG[3].z, REG[3].w);                                 \
        *reinterpret_cast<int4*>(smA + adst0) = w0;                            \
        *reinterpret_cast<int4*>(smA + adst1) = w1;                            \
    }

#define GLOADB_FT(K0)                                                          \
    _Pragma("unroll") for (int j = 0; j < 4; ++j) {                            \
        const int col = (gidx + j) * 4 + (l >> 4);                             \
        gload16(&Wb[(size_t)col * 768 + (K0) + (((l & 15) ^ (col & 15)) << 3)],\
                smB + (gidx + j) * 1024);                                      \
    }

// phase-2: B fragments, one fully-coalesced 1 KB load per (nt,ks)
#define LOADF(JB)                                                              \
    {                                                                          \
        const unsigned short* __restrict__ fb =                                \
            BpF + (size_t)(JB) * 16384 + wc * 4096 + l * 8;                    \
        _Pragma("unroll") for (int nt = 0; nt < 2; ++nt)                       \
            _Pragma("unroll") for (int ks = 0; ks < 4; ++ks)                   \
                bf[nt][ks] = *reinterpret_cast<const bf16x8*>(                 \
                    fb + nt * 2048 + ks * 512);                                \
    }

#define GEMM_STEP_LDS()                                                        \
    _Pragma("unroll") for (int ks = 0; ks < 4; ++ks) {                         \
        bf16x8 a[2], b[2];                                                     \
        _Pragma("unroll") for (int mt = 0; mt < 2; ++mt) {                     \
            const uint32_t row = (uint32_t)(wr * 32 + mt * 16 + fr);           \
            a[mt] = *reinterpret_cast<const bf16x8*>(                          \
                smA + row * 256u +                                             \
                (((uint32_t)(ks * 4 + h) ^ (row & 15u)) << 4));                \
        }                                                                      \
        _Pragma("unroll") for (int nt = 0; nt < 2; ++nt) {                     \
            const uint32_t col = (uint32_t)(wc * 32 + nt * 16 + fr);           \
            b[nt] = *reinterpret_cast<const bf16x8*>(                          \
                smB + col * 256u +                                             \
                (((uint32_t)(ks * 4 + h) ^ (col & 15u)) << 4));                \
        }                                                                      \
        _Pragma("unroll") for (int mt = 0; mt < 2; ++mt)                       \
            _Pragma("unroll") for (int nt = 0; nt < 2; ++nt)                   \
                acc[mt][nt] = __builtin_amdgcn_mfma_f32_16x16x32_bf16(         \
                    a[mt], b[nt], acc[mt][nt], 0, 0, 0);                       \
    }

#define GEMM_STEP_REG()                                                        \
    _Pragma("unroll") for (int ks = 0; ks < 4; ++ks) {                         \
        bf16x8 a[2];                                                           \
        _Pragma("unroll") for (int mt = 0; mt < 2; ++mt) {                     \
            const uint32_t row = (uint32_t)(wr * 32 + mt * 16 + fr);           \
            a[mt] = *reinterpret_cast<const bf16x8*>(                          \
                smA + row * 256u +                                             \
                (((uint32_t)(ks * 4 + h) ^ (row & 15u)) << 4));                \
        }                                                                      \
        _Pragma("unroll") for (int mt = 0; mt < 2; ++mt)                       \
            _Pragma("unroll") for (int nt = 0; nt < 2; ++nt)                   \
                acc[mt][nt] = __builtin_amdgcn_mfma_f32_16x16x32_bf16(         \
                    a[mt], bf[nt][ks], acc[mt][nt], 0, 0, 0);                  \
    }

#define DUMP_H(SO)                                                             \
    _Pragma("unroll") for (int nt = 0; nt < 2; ++nt) {                         \
        const int col = wc * 32 + nt * 16 + fr;                                \
        const float bv = bias[col];                                            \
        const int feat = (SO) + col;                                           \
        _Pragma("unroll") for (int mt = 0; mt < 2; ++mt) {                     \
            const int rowb = wr * 32 + mt * 16 + h * 4;                        \
            int2 o;                                                            \
            o.x = (int)pack2(acc[mt][nt][0] + bv, acc[mt][nt][1] + bv);        \
            o.y = (int)pack2(acc[mt][nt][2] + bv, acc[mt][nt][3] + bv);        \
            const uint32_t db = (uint32_t)feat * 128u +                        \
                ((uint32_t)((rowb >> 3) ^ (feat & 7)) << 4) +                  \
                (uint32_t)(rowb & 7) * 2u;                                     \
            *reinterpret_cast<int2*>(smHT + db) = o;                           \
            acc[mt][nt] = (f32x4){0.f, 0.f, 0.f, 0.f};                         \
        }                                                                      \
    }

#define LGKM_BAR()                                                             \
    asm volatile("s_waitcnt lgkmcnt(0)" ::: "memory");                         \
    __builtin_amdgcn_sched_barrier(0);                                         \
    __builtin_amdgcn_s_barrier();

    // ================= Phase 1: feature transform (both sides) =============
    FT_ISSUE(regY, 0);
    FT_ISSUE(regZ, 1);
#pragma unroll 1
    for (int pp = 0; pp < 6; ++pp) {
        // ---- even slot: tile 2pp ----
        FT_WRITE(regY);                       // compiler waits regY's loads
        GLOADB_FT(((2 * pp) % 6) * 128);
        __builtin_amdgcn_sched_barrier(0);    // pin: B gloads older than A issue
        if (pp < 5) {
            FT_ISSUE(regY, 2 * pp + 2);
            asm volatile("s_waitcnt vmcnt(4)" ::: "memory");   // B done, A flying
        } else {
            asm volatile("s_waitcnt vmcnt(0)" ::: "memory");
        }
        asm volatile("s_waitcnt lgkmcnt(0)" ::: "memory");
        __builtin_amdgcn_sched_barrier(0);
        __builtin_amdgcn_s_barrier();
        __builtin_amdgcn_s_setprio(1);
        GEMM_STEP_LDS();
        __builtin_amdgcn_s_setprio(0);
        LGKM_BAR();
        // ---- odd slot: tile 2pp+1 ----
        FT_WRITE(regZ);
        GLOADB_FT(((2 * pp + 1) % 6) * 128);
        __builtin_amdgcn_sched_barrier(0);
        if (pp < 5) {
            FT_ISSUE(regZ, 2 * pp + 3);
            asm volatile("s_waitcnt vmcnt(4)" ::: "memory");
        } else {
            asm volatile("s_waitcnt vmcnt(0)" ::: "memory");
        }
        asm volatile("s_waitcnt lgkmcnt(0)" ::: "memory");
        __builtin_amdgcn_sched_barrier(0);
        __builtin_amdgcn_s_barrier();
        __builtin_amdgcn_s_setprio(1);
        GEMM_STEP_LDS();
        __builtin_amdgcn_s_setprio(0);
        if (pp == 2) { DUMP_H(0); }           // side 0 complete
        if (pp == 5) { DUMP_H(128); }         // side 1 complete
        LGKM_BAR();
    }

    // ================= Phase 2: KAN1 GEMM (K = 256*16) =====================
#pragma unroll 1
    for (int jb = 0; jb < 32; ++jb) {
        // 1. Bp fragments -> regs (issued first; L2 latency hides under VALU)
        LOADF(jb);
        __builtin_amdgcn_sched_barrier(0);
        // 2. expansion: wave w -> feature jb*8+w, lane l -> row l
        {
            const int feat = jb * 8 + w;
            const unsigned short xv = *reinterpret_cast<const unsigned short*>(
                smHT + (uint32_t)feat * 128u +
                ((uint32_t)((l >> 3) ^ (feat & 7)) << 4) + (uint32_t)(l & 7) * 2u);
            const float x = bf2f(xv);
            float bs[8];
            bspline8(x, bs);
            const uint32_t pw0 = pack2(silu_f(x), bs[0]);
            const uint32_t pw1 = pack2(bs[1], bs[2]);
            const uint32_t pw2 = pack2(bs[3], bs[4]);
            const uint32_t pw3 = pack2(bs[5], bs[6]);
            const uint32_t pw4 = pack2(bs[7], 0.f);
            const uint32_t d0 = (uint32_t)l * 256u +
                ((uint32_t)((2 * w) ^ (l & 15)) << 4);
            const uint32_t d1 = (uint32_t)l * 256u +
                ((uint32_t)((2 * w + 1) ^ (l & 15)) << 4);
            *reinterpret_cast<int4*>(smA + d0) =
                make_int4((int)pw0, (int)pw1, (int)pw2, (int)pw3);
            *reinterpret_cast<int4*>(smA + d1) = make_int4((int)pw4, 0, 0, 0);
        }
        asm volatile("s_waitcnt lgkmcnt(0)" ::: "memory");
        __builtin_amdgcn_sched_barrier(0);
        __builtin_amdgcn_s_barrier();
        __builtin_amdgcn_s_setprio(1);
        GEMM_STEP_REG();
        __builtin_amdgcn_s_setprio(0);
        LGKM_BAR();
    }

    // ================= Phase 3: KAN2 + sigmoid =============================
    unsigned short* smH2 = (unsigned short*)lds;   // reuse smA/smB region
#pragma unroll
    for (int mt = 0; mt < 2; ++mt)
#pragma unroll
        for (int nt = 0; nt < 2; ++nt) {
            const int col = wc * 32 + nt * 16 + fr;
#pragma unroll
            for (int j = 0; j < 4; ++j) {
                const int row = wr * 32 + mt * 16 + h * 4 + j;
                smH2[row * 136 + col] = f2bf(acc[mt][nt][j]);
            }
        }
    __syncthreads();
    const int row2 = t >> 3, qd = t & 7;           // 8 threads/row, 16 cols each
    float sum = 0.f;
#pragma unroll 4
    for (int i = 0; i < 16; ++i) {
        const int j = qd * 16 + ((i + qd * 2) & 15);   // stagger banks
        const float x = bf2f(smH2[row2 * 136 + j]);
        float bs[8];
        bspline8(x, bs);
        const float4 s0 = *reinterpret_cast<const float4*>(&w2s[j * 8]);
        const float4 s1 = *reinterpret_cast<const float4*>(&w2s[j * 8 + 4]);
        float s = silu_f(x) * w2b[j];
        s += bs[0] * s0.x + bs[1] * s0.y + bs[2] * s0.z + bs[3] * s0.w;
        s += bs[4] * s1.x + bs[5] * s1.y + bs[6] * s1.z + bs[7] * s1.w;
        sum += s;
    }
    sum += __shfl_xor(sum, 1, 64);
    sum += __shfl_xor(sum, 2, 64);
    sum += __shfl_xor(sum, 4, 64);
    if (qd == 0) out[r0 + row2] = 1.0f / (1.0f + __expf(-sum));
}

// ---------------------------------------------------------------------------
extern "C" void kernel_launch(void* const* d_in, const int* in_sizes, int n_in,
                              void* d_out, int out_size, void* d_ws, size_t ws_size,
                              hipStream_t stream) {
    const float* stm  = (const float*)d_in[0];
    const float* nstm = (const float*)d_in[1];
    const float* ft_w = (const float*)d_in[2];
    const float* ft_b = (const float*)d_in[3];
    const float* k1bw = (const float*)d_in[4];
    const float* k1sw = (const float*)d_in[5];
    const float* k2bw = (const float*)d_in[6];
    const float* k2sw = (const float*)d_in[7];
    float* out = (float*)d_out;

    char* ws = (char*)d_ws;
    unsigned short* Wb  = (unsigned short*)ws;                //   196,608 B
    unsigned short* BpF = (unsigned short*)(ws + 196608);     // 1,048,576 B

    prep_ftw<<<384, 256, 0, stream>>>(ft_w, Wb);
    prep_bpf<<<2048, 256, 0, stream>>>(k1bw, k1sw, BpF);
    kan_fused<<<512, 512, 0, stream>>>(stm, nstm, Wb, ft_b, BpF, k2bw, k2sw, out);
}

// Round 20
// 92.909 us; speedup vs baseline: 1.1352x; 1.1239x over previous
//
#include <hip/hip_runtime.h>
#include <hip/hip_bf16.h>
#include <math.h>
#include <stdint.h>

typedef __attribute__((ext_vector_type(8))) short bf16x8;
typedef __attribute__((ext_vector_type(4))) float f32x4;

__device__ __forceinline__ uint32_t pack2(float a, float b) {
    union { __hip_bfloat162 h2; uint32_t u; } c;
    c.h2 = __float22bfloat162_rn(make_float2(a, b));   // v_cvt_pk_bf16_f32
    return c.u;
}
__device__ __forceinline__ unsigned short f2bf(float f) {
    union { __hip_bfloat16 h; unsigned short u; } c;
    c.h = __float2bfloat16(f);
    return c.u;
}
__device__ __forceinline__ float bf2f(unsigned short h) {
    union { uint32_t u; float f; } c; c.u = ((uint32_t)h) << 16;
    return c.f;
}
__device__ __forceinline__ float silu_f(float x) {
    return x / (1.0f + __expf(-x));
}

// Uniform cardinal cubic B-spline bases on grid g_i = -2.2 + 0.4*i.
// Identical to the reference Cox-de-Boor recursion on this uniform grid.
__device__ __forceinline__ void bspline8(float x, float* __restrict__ b) {
    const float tt = (x + 2.2f) * 2.5f;
#pragma unroll
    for (int v = 0; v < 8; ++v) {
        float y = fabsf(tt - (float)(v + 2));
        float p = fmaxf(2.0f - y, 0.0f);
        float q = fmaxf(1.0f - y, 0.0f);
        b[v] = (p * p * p - 4.0f * q * q * q) * (1.0f / 6.0f);
    }
}

__device__ __forceinline__ void gload16(const void* g, void* l) {
    __builtin_amdgcn_global_load_lds(
        (const __attribute__((address_space(1))) void*)g,
        (__attribute__((address_space(3))) void*)l, 16, 0, 0);
}

// ---------------------------------------------------------------------------
// prep kernels
// ---------------------------------------------------------------------------
__global__ __launch_bounds__(256) void prep_ftw(const float* __restrict__ ftw,
                                                unsigned short* __restrict__ Wb) {
    const int idx = blockIdx.x * 256 + threadIdx.x;   // 98304 = 128*768
    Wb[idx] = f2bf(ftw[idx]);
}

// bw (128x256) -> frag-contiguous for silu GEMM (K=256):
//   [wc(4)][nt(2)][ks(8)][l(64)][e(8)]; col = wc*32+nt*16+(l&15);
//   k(=feature) = ks*32 + (l>>4)*8 + e
__global__ __launch_bounds__(256) void prep_bwf(const float* __restrict__ bw,
                                                unsigned short* __restrict__ BwF) {
    const int idx = blockIdx.x * 256 + threadIdx.x;   // 32768
    const int e = idx & 7, l = (idx >> 3) & 63, ks = (idx >> 9) & 7;
    const int nt = (idx >> 12) & 1, wc = (idx >> 13) & 3;
    const int col = wc * 32 + nt * 16 + (l & 15);
    const int k = ks * 32 + (l >> 4) * 8 + e;
    BwF[idx] = f2bf(bw[col * 256 + k]);
}

// sw (128x256x8) -> frag-contiguous spline weights (K=2048):
//   [jb(32)][wc(4)][nt(2)][ks(2)][l(64)][e(8)]; col as above;
//   feature f = jb*8 + ks*4 + (l>>4);  basis v = e
__global__ __launch_bounds__(256) void prep_swf(const float* __restrict__ sw,
                                                unsigned short* __restrict__ SwF) {
    const int idx = blockIdx.x * 256 + threadIdx.x;   // 262144
    const int e = idx & 7, l = (idx >> 3) & 63, ks = (idx >> 9) & 1;
    const int nt = (idx >> 10) & 1, wc = (idx >> 11) & 3, jb = idx >> 13;
    const int col = wc * 32 + nt * 16 + (l & 15);
    const int f = jb * 8 + ks * 4 + (l >> 4);
    SwF[idx] = f2bf(sw[(size_t)(col * 256 + f) * 8 + e]);
}

// ---------------------------------------------------------------------------
// FUSED, BM=64, 2 blocks/CU (LDS 80 KB).  Per 64-row tile:
//   Phase 1: FT GEMM both sides (12 BK=128 tiles) -- identical to r17.
//            H -> smHT (transposed [256][64] bf16, chunk-XOR swizzled).
//   Phase 2: KAN1 as TWO DENSE GEMMs (no K padding; was 44% zeros):
//     2a. spline GEMM K=2048: 32 jb-steps of 8 features; expansion writes
//         8 bases as ONE int4 to phi_b [64][64] + silu as one b16 to
//         phi_s [64][256]; SwF frag-contiguous reg-B; 8 MFMA + 4 ds_read
//         per step (was 16 + 8).
//     2b. silu GEMM K=256 over phi_s at the end (32 MFMA), BwF reg-B.
//   Phase 3: KAN2 reduce + sigmoid.
// grid 512, block 512 (8 waves as 2x4; wave tile 32r x 32c).
// ---------------------------------------------------------------------------
__global__ __launch_bounds__(512, 4) void kan_fused(
        const float* __restrict__ stm, const float* __restrict__ nstm,
        const unsigned short* __restrict__ Wb, const float* __restrict__ bias,
        const unsigned short* __restrict__ BwF,
        const unsigned short* __restrict__ SwF,
        const float* __restrict__ w2b, const float* __restrict__ w2s,
        float* __restrict__ out) {
    __shared__ alignas(16) char lds[81920];
    char* smA  = lds;            // ph1: A tile (16 KB) | ph2a: phi_b [64][64] (8 KB)
    char* smB  = lds + 16384;    // ph1: Wb tile (32 KB)
    char* phiS = lds + 16384;    // ph2: phi_s [64 rows][256 k] bf16 (32 KB)
    char* smHT = lds + 49152;    // H^T [256 feat][64 rows] bf16, swizzled

    const int r0 = blockIdx.x * 64;
    const int t = threadIdx.x;
    const int l = t & 63, w = t >> 6;
    const int fr = l & 15, h = l >> 4;
    const int wr = w >> 2, wc = w & 3;        // 2x4 wave grid, tile 32r x 32c

    // A staging geometry: thread -> row (t>>3), 16 floats at col (t&7)*16
    const int arow = t >> 3;
    const int acol = (t & 7) * 16;
    const uint32_t adst0 = (uint32_t)arow * 256u +
        ((uint32_t)(((t & 7) * 2) ^ (arow & 15)) << 4);
    const uint32_t adst1 = (uint32_t)arow * 256u +
        ((uint32_t)(((t & 7) * 2 + 1) ^ (arow & 15)) << 4);
    const int gidx = w * 4;                   // gload instr base index

    f32x4 acc[2][2];
#pragma unroll
    for (int mt = 0; mt < 2; ++mt)
#pragma unroll
        for (int nt = 0; nt < 2; ++nt) acc[mt][nt] = (f32x4){0.f, 0.f, 0.f, 0.f};

    float4 regY[4], regZ[4];
    bf16x8 bsp[2][2];   // spline B fragments (static indexing only)
    bf16x8 bbw[2][4];   // silu-GEMM B fragments

#define FT_ISSUE(REG, TK)                                                      \
    {                                                                          \
        const float* __restrict__ Ap = ((TK) >= 6) ? nstm : stm;               \
        const int kk = ((TK) % 6) * 128;                                       \
        _Pragma("unroll") for (int q = 0; q < 4; ++q)                          \
            REG[q] = *reinterpret_cast<const float4*>(                         \
                &Ap[(size_t)(r0 + arow) * 768 + kk + acol + q * 4]);           \
    }

#define FT_WRITE(REG)                                                          \
    {                                                                          \
        int4 w0, w1;                                                           \
        w0.x = (int)pack2(REG[0].x, REG[0].y);                                 \
        w0.y = (int)pack2(REG[0].z, REG[0].w);                                 \
        w0.z = (int)pack2(REG[1].x, REG[1].y);                                 \
        w0.w = (int)pack2(REG[1].z, REG[1].w);                                 \
        w1.x = (int)pack2(REG[2].x, REG[2].y);                                 \
        w1.y = (int)pack2(REG[2].z, REG[2].w);                                 \
        w1.z = (int)pack2(REG[3].x, REG[3].y);                                 \
        w1.w = (int)pack2(REG[3].z, REG[3].w);                                 \
        *reinterpret_cast<int4*>(smA + adst0) = w0;                            \
        *reinterpret_cast<int4*>(smA + adst1) = w1;                            \
    }

#define GLOADB_FT(K0)                                                          \
    _Pragma("unroll") for (int j = 0; j < 4; ++j) {                            \
        const int col = (gidx + j) * 4 + (l >> 4);                             \
        gload16(&Wb[(size_t)col * 768 + (K0) + (((l & 15) ^ (col & 15)) << 3)],\
                smB + (gidx + j) * 1024);                                      \
    }

// spline B fragments: [jb][wc4][nt2][ks2][l64][e8], 1 KB coalesced each
#define LOADSP(JB)                                                             \
    {                                                                          \
        const unsigned short* __restrict__ fb =                                \
            SwF + (size_t)(JB) * 8192 + wc * 2048 + l * 8;                     \
        _Pragma("unroll") for (int nt = 0; nt < 2; ++nt)                       \
            _Pragma("unroll") for (int ks = 0; ks < 2; ++ks)                   \
                bsp[nt][ks] = *reinterpret_cast<const bf16x8*>(                \
                    fb + nt * 1024 + ks * 512);                                \
    }

// silu-GEMM B fragments, half HALF (ks 0..3 of 8): [wc4][nt2][ks8][l64][e8]
#define LOADBW(HALF)                                                           \
    {                                                                          \
        const unsigned short* __restrict__ fb =                                \
            BwF + wc * 8192 + (HALF) * 2048 + l * 8;                           \
        _Pragma("unroll") for (int nt = 0; nt < 2; ++nt)                       \
            _Pragma("unroll") for (int ks = 0; ks < 4; ++ks)                   \
                bbw[nt][ks] = *reinterpret_cast<const bf16x8*>(                \
                    fb + nt * 4096 + ks * 512);                                \
    }

#define GEMM_STEP_LDS()                                                        \
    _Pragma("unroll") for (int ks = 0; ks < 4; ++ks) {                         \
        bf16x8 a[2], b[2];                                                     \
        _Pragma("unroll") for (int mt = 0; mt < 2; ++mt) {                     \
            const uint32_t row = (uint32_t)(wr * 32 + mt * 16 + fr);           \
            a[mt] = *reinterpret_cast<const bf16x8*>(                          \
                smA + row * 256u +                                             \
                (((uint32_t)(ks * 4 + h) ^ (row & 15u)) << 4));                \
        }                                                                      \
        _Pragma("unroll") for (int nt = 0; nt < 2; ++nt) {                     \
            const uint32_t col = (uint32_t)(wc * 32 + nt * 16 + fr);           \
            b[nt] = *reinterpret_cast<const bf16x8*>(                          \
                smB + col * 256u +                                             \
                (((uint32_t)(ks * 4 + h) ^ (col & 15u)) << 4));                \
        }                                                                      \
        _Pragma("unroll") for (int mt = 0; mt < 2; ++mt)                       \
            _Pragma("unroll") for (int nt = 0; nt < 2; ++nt)                   \
                acc[mt][nt] = __builtin_amdgcn_mfma_f32_16x16x32_bf16(         \
                    a[mt], b[nt], acc[mt][nt], 0, 0, 0);                       \
    }

// spline GEMM step: K=64 (2 k-chunks), phi_b rows 128 B (8 chunks)
#define GEMM_SP()                                                              \
    _Pragma("unroll") for (int ks = 0; ks < 2; ++ks) {                         \
        bf16x8 a[2];                                                           \
        _Pragma("unroll") for (int mt = 0; mt < 2; ++mt) {                     \
            const uint32_t row = (uint32_t)(wr * 32 + mt * 16 + fr);           \
            a[mt] = *reinterpret_cast<const bf16x8*>(                          \
                smA + row * 128u +                                             \
                (((uint32_t)(ks * 4 + h) ^ (row & 7u)) << 4));                 \
        }                                                                      \
        _Pragma("unroll") for (int mt = 0; mt < 2; ++mt)                       \
            _Pragma("unroll") for (int nt = 0; nt < 2; ++nt)                   \
                acc[mt][nt] = __builtin_amdgcn_mfma_f32_16x16x32_bf16(         \
                    a[mt], bsp[nt][ks], acc[mt][nt], 0, 0, 0);                 \
    }

// silu GEMM half: 4 k-chunks from phi_s (rows 512 B = 32 chunks)
#define GEMM_BW(HALF)                                                          \
    _Pragma("unroll") for (int ks = 0; ks < 4; ++ks) {                         \
        bf16x8 a[2];                                                           \
        _Pragma("unroll") for (int mt = 0; mt < 2; ++mt) {                     \
            const uint32_t row = (uint32_t)(wr * 32 + mt * 16 + fr);           \
            a[mt] = *reinterpret_cast<const bf16x8*>(                          \
                phiS + row * 512u +                                            \
                (((uint32_t)(((HALF) * 4 + ks) * 4 + h) ^ (row & 15u)) << 4)); \
        }                                                                      \
        _Pragma("unroll") for (int mt = 0; mt < 2; ++mt)                       \
            _Pragma("unroll") for (int nt = 0; nt < 2; ++nt)                   \
                acc[mt][nt] = __builtin_amdgcn_mfma_f32_16x16x32_bf16(         \
                    a[mt], bbw[nt][ks], acc[mt][nt], 0, 0, 0);                 \
    }

#define DUMP_H(SO)                                                             \
    _Pragma("unroll") for (int nt = 0; nt < 2; ++nt) {                         \
        const int col = wc * 32 + nt * 16 + fr;                                \
        const float bv = bias[col];                                            \
        const int feat = (SO) + col;                                           \
        _Pragma("unroll") for (int mt = 0; mt < 2; ++mt) {                     \
            const int rowb = wr * 32 + mt * 16 + h * 4;                        \
            int2 o;                                                            \
            o.x = (int)pack2(acc[mt][nt][0] + bv, acc[mt][nt][1] + bv);        \
            o.y = (int)pack2(acc[mt][nt][2] + bv, acc[mt][nt][3] + bv);        \
            const uint32_t db = (uint32_t)feat * 128u +                        \
                ((uint32_t)((rowb >> 3) ^ (feat & 7)) << 4) +                  \
                (uint32_t)(rowb & 7) * 2u;                                     \
            *reinterpret_cast<int2*>(smHT + db) = o;                           \
            acc[mt][nt] = (f32x4){0.f, 0.f, 0.f, 0.f};                         \
        }                                                                      \
    }

#define LGKM_BAR()                                                             \
    asm volatile("s_waitcnt lgkmcnt(0)" ::: "memory");                         \
    __builtin_amdgcn_sched_barrier(0);                                         \
    __builtin_amdgcn_s_barrier();

    // ================= Phase 1: feature transform (both sides) =============
    FT_ISSUE(regY, 0);
    FT_ISSUE(regZ, 1);
#pragma unroll 1
    for (int pp = 0; pp < 6; ++pp) {
        // ---- even slot: tile 2pp ----
        FT_WRITE(regY);                       // compiler waits regY's loads
        GLOADB_FT(((2 * pp) % 6) * 128);
        __builtin_amdgcn_sched_barrier(0);    // pin: B gloads older than A issue
        if (pp < 5) {
            FT_ISSUE(regY, 2 * pp + 2);
            asm volatile("s_waitcnt vmcnt(4)" ::: "memory");   // B done, A flying
        } else {
            asm volatile("s_waitcnt vmcnt(0)" ::: "memory");
        }
        asm volatile("s_waitcnt lgkmcnt(0)" ::: "memory");
        __builtin_amdgcn_sched_barrier(0);
        __builtin_amdgcn_s_barrier();
        __builtin_amdgcn_s_setprio(1);
        GEMM_STEP_LDS();
        __builtin_amdgcn_s_setprio(0);
        LGKM_BAR();
        // ---- odd slot: tile 2pp+1 ----
        FT_WRITE(regZ);
        GLOADB_FT(((2 * pp + 1) % 6) * 128);
        __builtin_amdgcn_sched_barrier(0);
        if (pp < 5) {
            FT_ISSUE(regZ, 2 * pp + 3);
            asm volatile("s_waitcnt vmcnt(4)" ::: "memory");
        } else {
            asm volatile("s_waitcnt vmcnt(0)" ::: "memory");
        }
        asm volatile("s_waitcnt lgkmcnt(0)" ::: "memory");
        __builtin_amdgcn_sched_barrier(0);
        __builtin_amdgcn_s_barrier();
        __builtin_amdgcn_s_setprio(1);
        GEMM_STEP_LDS();
        __builtin_amdgcn_s_setprio(0);
        if (pp == 2) { DUMP_H(0); }           // side 0 complete
        if (pp == 5) { DUMP_H(128); }         // side 1 complete
        LGKM_BAR();
    }

    // ================= Phase 2a: spline GEMM (K = 2048, dense) =============
#pragma unroll 1
    for (int jb = 0; jb < 32; ++jb) {
        // 1. spline B fragments -> regs (L2 latency hides under expansion)
        LOADSP(jb);
        __builtin_amdgcn_sched_barrier(0);
        // 2. expansion: wave w -> feature jb*8+w, lane l -> row l
        //    bases -> phi_b (one int4); silu -> phi_s (one b16)
        {
            const int feat = jb * 8 + w;
            const unsigned short xv = *reinterpret_cast<const unsigned short*>(
                smHT + (uint32_t)feat * 128u +
                ((uint32_t)((l >> 3) ^ (feat & 7)) << 4) + (uint32_t)(l & 7) * 2u);
            const float x = bf2f(xv);
            float bs[8];
            bspline8(x, bs);
            const uint32_t pw0 = pack2(bs[0], bs[1]);
            const uint32_t pw1 = pack2(bs[2], bs[3]);
            const uint32_t pw2 = pack2(bs[4], bs[5]);
            const uint32_t pw3 = pack2(bs[6], bs[7]);
            const uint32_t db = (uint32_t)l * 128u +
                ((uint32_t)(w ^ (l & 7)) << 4);
            *reinterpret_cast<int4*>(smA + db) =
                make_int4((int)pw0, (int)pw1, (int)pw2, (int)pw3);
            const uint32_t ds = (uint32_t)l * 512u +
                ((uint32_t)(jb ^ (l & 15)) << 4) + (uint32_t)w * 2u;
            *reinterpret_cast<unsigned short*>(phiS + ds) = f2bf(silu_f(x));
        }
        asm volatile("s_waitcnt lgkmcnt(0)" ::: "memory");
        __builtin_amdgcn_sched_barrier(0);
        __builtin_amdgcn_s_barrier();
        __builtin_amdgcn_s_setprio(1);
        GEMM_SP();
        __builtin_amdgcn_s_setprio(0);
        LGKM_BAR();
    }

    // ================= Phase 2b: silu GEMM (K = 256, dense) ================
    // phi_s fully written and visible (each step ended with lgkm+barrier).
    LOADBW(0);
    __builtin_amdgcn_s_setprio(1);
    GEMM_BW(0);
    __builtin_amdgcn_s_setprio(0);
    LOADBW(1);
    __builtin_amdgcn_s_setprio(1);
    GEMM_BW(1);
    __builtin_amdgcn_s_setprio(0);
    LGKM_BAR();

    // ================= Phase 3: KAN2 + sigmoid =============================
    unsigned short* smH2 = (unsigned short*)lds;   // reuse smA/phiS region
#pragma unroll
    for (int mt = 0; mt < 2; ++mt)
#pragma unroll
        for (int nt = 0; nt < 2; ++nt) {
            const int col = wc * 32 + nt * 16 + fr;
#pragma unroll
            for (int j = 0; j < 4; ++j) {
                const int row = wr * 32 + mt * 16 + h * 4 + j;
                smH2[row * 136 + col] = f2bf(acc[mt][nt][j]);
            }
        }
    __syncthreads();
    const int row2 = t >> 3, qd = t & 7;           // 8 threads/row, 16 cols each
    float sum = 0.f;
#pragma unroll 4
    for (int i = 0; i < 16; ++i) {
        const int j = qd * 16 + ((i + qd * 2) & 15);   // stagger banks
        const float x = bf2f(smH2[row2 * 136 + j]);
        float bs[8];
        bspline8(x, bs);
        const float4 s0 = *reinterpret_cast<const float4*>(&w2s[j * 8]);
        const float4 s1 = *reinterpret_cast<const float4*>(&w2s[j * 8 + 4]);
        float s = silu_f(x) * w2b[j];
        s += bs[0] * s0.x + bs[1] * s0.y + bs[2] * s0.z + bs[3] * s0.w;
        s += bs[4] * s1.x + bs[5] * s1.y + bs[6] * s1.z + bs[7] * s1.w;
        sum += s;
    }
    sum += __shfl_xor(sum, 1, 64);
    sum += __shfl_xor(sum, 2, 64);
    sum += __shfl_xor(sum, 4, 64);
    if (qd == 0) out[r0 + row2] = 1.0f / (1.0f + __expf(-sum));
}

// ---------------------------------------------------------------------------
extern "C" void kernel_launch(void* const* d_in, const int* in_sizes, int n_in,
                              void* d_out, int out_size, void* d_ws, size_t ws_size,
                              hipStream_t stream) {
    const float* stm  = (const float*)d_in[0];
    const float* nstm = (const float*)d_in[1];
    const float* ft_w = (const float*)d_in[2];
    const float* ft_b = (const float*)d_in[3];
    const float* k1bw = (const float*)d_in[4];
    const float* k1sw = (const float*)d_in[5];
    const float* k2bw = (const float*)d_in[6];
    const float* k2sw = (const float*)d_in[7];
    float* out = (float*)d_out;

    char* ws = (char*)d_ws;
    unsigned short* Wb  = (unsigned short*)ws;                //   196,608 B
    unsigned short* BwF = (unsigned short*)(ws + 196608);     //    65,536 B
    unsigned short* SwF = (unsigned short*)(ws + 262144);     //   524,288 B

    prep_ftw<<<384, 256, 0, stream>>>(ft_w, Wb);
    prep_bwf<<<128, 256, 0, stream>>>(k1bw, BwF);
    prep_swf<<<1024, 256, 0, stream>>>(k1sw, SwF);
    kan_fused<<<512, 512, 0, stream>>>(stm, nstm, Wb, ft_b, BwF, SwF,
                                       k2bw, k2sw, out);
}